// Round 1
// baseline (583.886 us; speedup 1.0000x reference)
//
#include <hip/hip_runtime.h>
#include <hip/hip_bf16.h>
#include <stdint.h>

#define LN_EPS 1e-6f

typedef __bf16 bf16x8 __attribute__((ext_vector_type(8)));
typedef float f32x4 __attribute__((ext_vector_type(4)));

// float -> bf16 (RNE), manual to avoid any __bf16 conversion lowering surprises
__device__ __forceinline__ unsigned short f2bf(float f) {
    uint32_t u = __float_as_uint(f);
    uint32_t r = (u + 0x7fffu + ((u >> 16) & 1u)) >> 16;
    return (unsigned short)r;
}

// async 16B global -> LDS (wave-uniform LDS base + lane*16 semantics)
__device__ __forceinline__ void async_copy16(const void* g, void* l) {
    const __attribute__((address_space(1))) uint32_t* gp =
        (const __attribute__((address_space(1))) uint32_t*)(uintptr_t)g;
    // generic LDS address: low 32 bits are the LDS byte offset (aperture is 2^32-aligned)
    __attribute__((address_space(3))) uint32_t* lp =
        (__attribute__((address_space(3))) uint32_t*)(uint32_t)(uintptr_t)l;
    __builtin_amdgcn_global_load_lds(gp, lp, 16, 0, 0);
}

// ---------------- LayerNorm + cast to bf16 ----------------
// one block (256 thr) per row of H=4096; grid.y selects problem
__global__ __launch_bounds__(256) void ln_bf16_kernel(
    const float* __restrict__ x0, const float* __restrict__ x1,
    const float* __restrict__ s0, const float* __restrict__ b0,
    const float* __restrict__ s1, const float* __restrict__ b1,
    unsigned short* __restrict__ y0, unsigned short* __restrict__ y1, int H)
{
    int row = blockIdx.x;
    int prob = blockIdx.y;
    const float* x = (prob ? x1 : x0) + (size_t)row * H;
    const float* s = prob ? s1 : s0;
    const float* b = prob ? b1 : b0;
    unsigned short* y = (prob ? y1 : y0) + (size_t)row * H;
    int t = threadIdx.x;

    float4 v[4];
    float sum = 0.f, sq = 0.f;
#pragma unroll
    for (int g = 0; g < 4; ++g) {
        v[g] = ((const float4*)x)[t + 256 * g];
        sum += v[g].x + v[g].y + v[g].z + v[g].w;
        sq  += v[g].x * v[g].x + v[g].y * v[g].y + v[g].z * v[g].z + v[g].w * v[g].w;
    }
#pragma unroll
    for (int off = 32; off > 0; off >>= 1) {
        sum += __shfl_xor(sum, off, 64);
        sq  += __shfl_xor(sq, off, 64);
    }
    __shared__ float ssum[4], ssq[4];
    int wave = t >> 6;
    if ((t & 63) == 0) { ssum[wave] = sum; ssq[wave] = sq; }
    __syncthreads();
    sum = ssum[0] + ssum[1] + ssum[2] + ssum[3];
    sq  = ssq[0] + ssq[1] + ssq[2] + ssq[3];
    float mu = sum * (1.0f / 4096.0f);
    float var = sq * (1.0f / 4096.0f) - mu * mu;
    float rstd = rsqrtf(var + LN_EPS);

#pragma unroll
    for (int g = 0; g < 4; ++g) {
        int i4 = t + 256 * g;
        float4 sc = ((const float4*)s)[i4];
        float4 bi = ((const float4*)b)[i4];
        ushort4 o;
        o.x = f2bf((v[g].x - mu) * rstd * sc.x + bi.x);
        o.y = f2bf((v[g].y - mu) * rstd * sc.y + bi.y);
        o.z = f2bf((v[g].z - mu) * rstd * sc.z + bi.z);
        o.w = f2bf((v[g].w - mu) * rstd * sc.w + bi.w);
        ((ushort4*)y)[i4] = o;
    }
}

// ---------------- cast + transpose W (K x N fp32) -> Wt (N x K bf16) ----------------
__global__ __launch_bounds__(256) void cast_transpose_kernel(
    const float* __restrict__ w0, const float* __restrict__ w1,
    unsigned short* __restrict__ o0, unsigned short* __restrict__ o1,
    int K, int N)
{
    int prob = blockIdx.z;
    const float* w = prob ? w1 : w0;
    unsigned short* o = prob ? o1 : o0;
    __shared__ unsigned short tile[32][33];
    int tx = threadIdx.x & 31;
    int ty = threadIdx.x >> 5;  // 0..7
    int n0 = blockIdx.x * 32;
    int k0 = blockIdx.y * 32;
#pragma unroll
    for (int i = 0; i < 4; ++i) {
        int k = ty + 8 * i;
        tile[k][tx] = f2bf(w[(size_t)(k0 + k) * N + n0 + tx]);
    }
    __syncthreads();
#pragma unroll
    for (int i = 0; i < 4; ++i) {
        int n = ty + 8 * i;
        o[(size_t)(n0 + n) * K + k0 + tx] = tile[tx][n];
    }
}

// ---------------- bf16 GEMM: out[M,N] = A[M,K] * Wt[N,K]^T + bias ----------------
#define BM 128
#define BN 128
#define BK 32

__global__ __launch_bounds__(256) void gemm_bf16_kernel(
    const unsigned short* __restrict__ A0, const unsigned short* __restrict__ A1,
    const unsigned short* __restrict__ W0, const unsigned short* __restrict__ W1,
    const float* __restrict__ bias0, const float* __restrict__ bias1,
    float* __restrict__ out0, float* __restrict__ out1,
    int M, int N, int K)
{
    int prob = blockIdx.z;
    const unsigned short* A = prob ? A1 : A0;
    const unsigned short* W = prob ? W1 : W0;
    const float* bias = prob ? bias1 : bias0;
    float* out = prob ? out1 : out0;

    __shared__ unsigned short As[BM * BK];  // [row][k] contiguous, 8 KB
    __shared__ unsigned short Bs[BN * BK];  // [n][k] contiguous, 8 KB

    int t = threadIdx.x;
    int wave = t >> 6, lane = t & 63;
    int quad = lane >> 4, r16 = lane & 15;
    int wm = wave >> 1, wn = wave & 1;

    int tile_m = blockIdx.y * BM;
    int tile_n = blockIdx.x * BN;

    f32x4 acc[4][4] = {};

    for (int k0 = 0; k0 < K; k0 += BK) {
        // stage A-tile and B-tile: 512 x 16B chunks each, 2 per thread per tile
#pragma unroll
        for (int q = 0; q < 2; ++q) {
            int c = wave * 128 + q * 64 + lane;   // chunk id 0..511
            int row = c >> 2, kb = c & 3;
            const unsigned short* ga = A + (size_t)(tile_m + row) * K + k0 + kb * 8;
            const unsigned short* gb = W + (size_t)(tile_n + row) * K + k0 + kb * 8;
            uint32_t lbase = (uint32_t)(wave * 128 + q * 64) * 16;  // wave-uniform
            async_copy16(ga, (char*)As + lbase);
            async_copy16(gb, (char*)Bs + lbase);
        }
        __syncthreads();  // drains vmcnt (global_load_lds) + barrier

        bf16x8 af[4], bfr[4];
#pragma unroll
        for (int i = 0; i < 4; ++i) {
            af[i]  = *(const bf16x8*)((const char*)As + (wm * 64 + i * 16 + r16) * 64 + quad * 16);
            bfr[i] = *(const bf16x8*)((const char*)Bs + (wn * 64 + i * 16 + r16) * 64 + quad * 16);
        }
#pragma unroll
        for (int i = 0; i < 4; ++i)
#pragma unroll
            for (int j = 0; j < 4; ++j)
                acc[i][j] = __builtin_amdgcn_mfma_f32_16x16x32_bf16(af[i], bfr[j], acc[i][j], 0, 0, 0);
        __syncthreads();  // protect LDS before next stage
    }

    // epilogue: C mapping col=lane&15, row=quad*4+reg
#pragma unroll
    for (int j = 0; j < 4; ++j) {
        int col = tile_n + wn * 64 + j * 16 + r16;
        float bj = bias[col];
#pragma unroll
        for (int i = 0; i < 4; ++i) {
            int row = tile_m + wm * 64 + i * 16 + quad * 4;
#pragma unroll
            for (int r = 0; r < 4; ++r)
                out[(size_t)(row + r) * N + col] = acc[i][j][r] + bj;
        }
    }
}

extern "C" void kernel_launch(void* const* d_in, const int* in_sizes, int n_in,
                              void* d_out, int out_size, void* d_ws, size_t ws_size,
                              hipStream_t stream) {
    const float* xv = (const float*)d_in[0];
    const float* xt = (const float*)d_in[1];
    const float* sv = (const float*)d_in[2];
    const float* bv = (const float*)d_in[3];
    const float* wv = (const float*)d_in[4];
    const float* biasv = (const float*)d_in[5];
    const float* st = (const float*)d_in[6];
    const float* bt = (const float*)d_in[7];
    const float* wt = (const float*)d_in[8];
    const float* biast = (const float*)d_in[9];
    float* out = (float*)d_out;

    const int B = 2, S = 4096, H = 4096, P = 1024;
    const int M = B * S;  // 8192
    float* outv = out;
    float* outt = out + (size_t)M * P;

    size_t xnBytes = (size_t)M * H * 2;  // 64 MiB per problem
    size_t wtBytes = (size_t)P * H * 2;  // 8 MiB per problem
    char* ws = (char*)d_ws;

    if (ws_size >= 2 * xnBytes + 2 * wtBytes) {
        unsigned short* Xv = (unsigned short*)(ws);
        unsigned short* Xt = (unsigned short*)(ws + xnBytes);
        unsigned short* Wv = (unsigned short*)(ws + 2 * xnBytes);
        unsigned short* Wt = (unsigned short*)(ws + 2 * xnBytes + wtBytes);
        ln_bf16_kernel<<<dim3(M, 2), 256, 0, stream>>>(xv, xt, sv, bv, st, bt, Xv, Xt, H);
        cast_transpose_kernel<<<dim3(P / 32, H / 32, 2), 256, 0, stream>>>(wv, wt, Wv, Wt, H, P);
        gemm_bf16_kernel<<<dim3(P / BN, M / BM, 2), 256, 0, stream>>>(
            Xv, Xt, Wv, Wt, biasv, biast, outv, outt, M, P, H);
    } else {
        // sequential fallback: reuse one Xn + one Wt buffer (needs 72 MiB)
        unsigned short* X  = (unsigned short*)(ws);
        unsigned short* Wb = (unsigned short*)(ws + xnBytes);
        ln_bf16_kernel<<<dim3(M, 1), 256, 0, stream>>>(xv, xv, sv, bv, sv, bv, X, X, H);
        cast_transpose_kernel<<<dim3(P / 32, H / 32, 1), 256, 0, stream>>>(wv, wv, Wb, Wb, H, P);
        gemm_bf16_kernel<<<dim3(P / BN, M / BM, 1), 256, 0, stream>>>(
            X, X, Wb, Wb, biasv, biasv, outv, outv, M, P, H);
        ln_bf16_kernel<<<dim3(M, 1), 256, 0, stream>>>(xt, xt, st, bt, st, bt, X, X, H);
        cast_transpose_kernel<<<dim3(P / 32, H / 32, 1), 256, 0, stream>>>(wt, wt, Wb, Wb, H, P);
        gemm_bf16_kernel<<<dim3(P / BN, M / BM, 1), 256, 0, stream>>>(
            X, X, Wb, Wb, biast, biast, outt, outt, M, P, H);
    }
}

// Round 2
// 555.242 us; speedup vs baseline: 1.0516x; 1.0516x over previous
//
#include <hip/hip_runtime.h>
#include <hip/hip_bf16.h>
#include <stdint.h>

#define LN_EPS 1e-6f

typedef __bf16 bf16x8 __attribute__((ext_vector_type(8)));
typedef float f32x4 __attribute__((ext_vector_type(4)));

// float -> bf16 (RNE)
__device__ __forceinline__ unsigned short f2bf(float f) {
    uint32_t u = __float_as_uint(f);
    uint32_t r = (u + 0x7fffu + ((u >> 16) & 1u)) >> 16;
    return (unsigned short)r;
}

// async 16B global -> LDS (wave-uniform LDS base + lane*16 semantics)
__device__ __forceinline__ void async_copy16(const void* g, void* l) {
    const __attribute__((address_space(1))) uint32_t* gp =
        (const __attribute__((address_space(1))) uint32_t*)(uintptr_t)g;
    __attribute__((address_space(3))) uint32_t* lp =
        (__attribute__((address_space(3))) uint32_t*)(uint32_t)(uintptr_t)l;
    __builtin_amdgcn_global_load_lds(gp, lp, 16, 0, 0);
}

// ---------------- LayerNorm + cast to bf16 ----------------
__global__ __launch_bounds__(256) void ln_bf16_kernel(
    const float* __restrict__ x0, const float* __restrict__ x1,
    const float* __restrict__ s0, const float* __restrict__ b0,
    const float* __restrict__ s1, const float* __restrict__ b1,
    unsigned short* __restrict__ y0, unsigned short* __restrict__ y1, int H)
{
    int row = blockIdx.x;
    int prob = blockIdx.y;
    const float* x = (prob ? x1 : x0) + (size_t)row * H;
    const float* s = prob ? s1 : s0;
    const float* b = prob ? b1 : b0;
    unsigned short* y = (prob ? y1 : y0) + (size_t)row * H;
    int t = threadIdx.x;

    float4 v[4];
    float sum = 0.f, sq = 0.f;
#pragma unroll
    for (int g = 0; g < 4; ++g) {
        v[g] = ((const float4*)x)[t + 256 * g];
        sum += v[g].x + v[g].y + v[g].z + v[g].w;
        sq  += v[g].x * v[g].x + v[g].y * v[g].y + v[g].z * v[g].z + v[g].w * v[g].w;
    }
#pragma unroll
    for (int off = 32; off > 0; off >>= 1) {
        sum += __shfl_xor(sum, off, 64);
        sq  += __shfl_xor(sq, off, 64);
    }
    __shared__ float ssum[4], ssq[4];
    int wave = t >> 6;
    if ((t & 63) == 0) { ssum[wave] = sum; ssq[wave] = sq; }
    __syncthreads();
    sum = ssum[0] + ssum[1] + ssum[2] + ssum[3];
    sq  = ssq[0] + ssq[1] + ssq[2] + ssq[3];
    float mu = sum * (1.0f / 4096.0f);
    float var = sq * (1.0f / 4096.0f) - mu * mu;
    float rstd = rsqrtf(var + LN_EPS);

#pragma unroll
    for (int g = 0; g < 4; ++g) {
        int i4 = t + 256 * g;
        float4 sc = ((const float4*)s)[i4];
        float4 bi = ((const float4*)b)[i4];
        ushort4 o;
        o.x = f2bf((v[g].x - mu) * rstd * sc.x + bi.x);
        o.y = f2bf((v[g].y - mu) * rstd * sc.y + bi.y);
        o.z = f2bf((v[g].z - mu) * rstd * sc.z + bi.z);
        o.w = f2bf((v[g].w - mu) * rstd * sc.w + bi.w);
        ((ushort4*)y)[i4] = o;
    }
}

// ---------------- cast + transpose W (K x N fp32) -> Wt (N x K bf16) ----------------
__global__ __launch_bounds__(256) void cast_transpose_kernel(
    const float* __restrict__ w0, const float* __restrict__ w1,
    unsigned short* __restrict__ o0, unsigned short* __restrict__ o1,
    int K, int N)
{
    int prob = blockIdx.z;
    const float* w = prob ? w1 : w0;
    unsigned short* o = prob ? o1 : o0;
    __shared__ unsigned short tile[32][33];
    int tx = threadIdx.x & 31;
    int ty = threadIdx.x >> 5;
    int n0 = blockIdx.x * 32;
    int k0 = blockIdx.y * 32;
#pragma unroll
    for (int i = 0; i < 4; ++i) {
        int k = ty + 8 * i;
        tile[k][tx] = f2bf(w[(size_t)(k0 + k) * N + n0 + tx]);
    }
    __syncthreads();
#pragma unroll
    for (int i = 0; i < 4; ++i) {
        int n = ty + 8 * i;
        o[(size_t)(n0 + n) * K + k0 + tx] = tile[tx][n];
    }
}

// ---------------- bf16 GEMM: out[M,N] = A[M,K] * Wt[N,K]^T + bias ----------------
// 1-D grid, XCD-aware swizzle. Block tile 128x128, BK=64, 4 waves, 4x4 16x16x32 MFMA/wave.
#define BM 128
#define BN 128
#define BK 64

__global__ __launch_bounds__(256) void gemm_bf16_kernel(
    const unsigned short* __restrict__ A0, const unsigned short* __restrict__ A1,
    const unsigned short* __restrict__ W0, const unsigned short* __restrict__ W1,
    const float* __restrict__ bias0, const float* __restrict__ bias1,
    float* __restrict__ out0, float* __restrict__ out1,
    int M, int N, int K)
{
    // XCD-aware decode: xcd = id&7 owns m-tiles [xcd*8, xcd*8+8); n varies fastest
    // so the 8 blocks sharing an A-panel are consecutive on ONE XCD's L2.
    int id = blockIdx.x;
    int xcd = id & 7;
    int l = id >> 3;            // sequence number within XCD
    int prob = l >> 6;          // 64 blocks per problem per XCD (grid=512 -> always 0)
    int rem = l & 63;
    int mt = xcd * 8 + (rem >> 3);
    int nt = rem & 7;

    const unsigned short* A = prob ? A1 : A0;
    const unsigned short* W = prob ? W1 : W0;
    const float* bias = prob ? bias1 : bias0;
    float* out = prob ? out1 : out0;

    __shared__ unsigned short As[BM * BK];  // [row][k], 128B per row, 16 KB
    __shared__ unsigned short Bs[BN * BK];

    int t = threadIdx.x;
    int wave = t >> 6, lane = t & 63;
    int quad = lane >> 4, r16 = lane & 15;
    int wm = wave >> 1, wn = wave & 1;

    int tile_m = mt * BM;
    int tile_n = nt * BN;

    // per-thread staging addresses (advance by k0 each iter)
    int c = t;                        // chunk ids t, t+256, t+512, t+768
    const unsigned short* ga[4];
    const unsigned short* gb[4];
#pragma unroll
    for (int q = 0; q < 4; ++q) {
        int cc = q * 256 + t;
        int row = cc >> 3, kb = cc & 7;
        ga[q] = A + (size_t)(tile_m + row) * K + kb * 8;
        gb[q] = W + (size_t)(tile_n + row) * K + kb * 8;
    }
    (void)c;

    f32x4 acc[4][4] = {};

    for (int k0 = 0; k0 < K; k0 += BK) {
#pragma unroll
        for (int q = 0; q < 4; ++q) {
            uint32_t lbase = (uint32_t)(q * 256 + wave * 64) * 16;  // wave-uniform
            async_copy16(ga[q] + k0, (char*)As + lbase);
            async_copy16(gb[q] + k0, (char*)Bs + lbase);
        }
        __syncthreads();

#pragma unroll
        for (int s = 0; s < 2; ++s) {
            bf16x8 af[4], bfr[4];
#pragma unroll
            for (int i = 0; i < 4; ++i) {
                af[i]  = *(const bf16x8*)(As + (wm * 64 + i * 16 + r16) * 64 + (s * 4 + quad) * 8);
                bfr[i] = *(const bf16x8*)(Bs + (wn * 64 + i * 16 + r16) * 64 + (s * 4 + quad) * 8);
            }
#pragma unroll
            for (int i = 0; i < 4; ++i)
#pragma unroll
                for (int j = 0; j < 4; ++j)
                    acc[i][j] = __builtin_amdgcn_mfma_f32_16x16x32_bf16(af[i], bfr[j], acc[i][j], 0, 0, 0);
        }
        __syncthreads();
    }

    // epilogue: C mapping col=lane&15, row=quad*4+reg
#pragma unroll
    for (int j = 0; j < 4; ++j) {
        int col = tile_n + wn * 64 + j * 16 + r16;
        float bj = bias[col];
#pragma unroll
        for (int i = 0; i < 4; ++i) {
            int row = tile_m + wm * 64 + i * 16 + quad * 4;
#pragma unroll
            for (int r = 0; r < 4; ++r)
                out[(size_t)(row + r) * N + col] = acc[i][j][r] + bj;
        }
    }
}

extern "C" void kernel_launch(void* const* d_in, const int* in_sizes, int n_in,
                              void* d_out, int out_size, void* d_ws, size_t ws_size,
                              hipStream_t stream) {
    const float* xv = (const float*)d_in[0];
    const float* xt = (const float*)d_in[1];
    const float* sv = (const float*)d_in[2];
    const float* bv = (const float*)d_in[3];
    const float* wv = (const float*)d_in[4];
    const float* biasv = (const float*)d_in[5];
    const float* st = (const float*)d_in[6];
    const float* bt = (const float*)d_in[7];
    const float* wt = (const float*)d_in[8];
    const float* biast = (const float*)d_in[9];
    float* out = (float*)d_out;

    const int B = 2, S = 4096, H = 4096, P = 1024;
    const int M = B * S;  // 8192
    float* outv = out;
    float* outt = out + (size_t)M * P;

    size_t xnBytes = (size_t)M * H * 2;  // 64 MiB per problem
    size_t wtBytes = (size_t)P * H * 2;  // 8 MiB per problem
    char* ws = (char*)d_ws;

    if (ws_size >= 2 * xnBytes + 2 * wtBytes) {
        unsigned short* Xv = (unsigned short*)(ws);
        unsigned short* Xt = (unsigned short*)(ws + xnBytes);
        unsigned short* Wv = (unsigned short*)(ws + 2 * xnBytes);
        unsigned short* Wt = (unsigned short*)(ws + 2 * xnBytes + wtBytes);
        ln_bf16_kernel<<<dim3(M, 2), 256, 0, stream>>>(xv, xt, sv, bv, st, bt, Xv, Xt, H);
        cast_transpose_kernel<<<dim3(P / 32, H / 32, 2), 256, 0, stream>>>(wv, wt, Wv, Wt, H, P);
        // 2 problems x 64 m-tiles x 8 n-tiles = 1024 blocks
        gemm_bf16_kernel<<<dim3(1024), 256, 0, stream>>>(
            Xv, Xt, Wv, Wt, biasv, biast, outv, outt, M, P, H);
    } else {
        unsigned short* X  = (unsigned short*)(ws);
        unsigned short* Wb = (unsigned short*)(ws + xnBytes);
        ln_bf16_kernel<<<dim3(M, 1), 256, 0, stream>>>(xv, xv, sv, bv, sv, bv, X, X, H);
        cast_transpose_kernel<<<dim3(P / 32, H / 32, 1), 256, 0, stream>>>(wv, wv, Wb, Wb, H, P);
        gemm_bf16_kernel<<<dim3(512), 256, 0, stream>>>(
            X, X, Wb, Wb, biasv, biasv, outv, outv, M, P, H);
        ln_bf16_kernel<<<dim3(M, 1), 256, 0, stream>>>(xt, xt, st, bt, st, bt, X, X, H);
        cast_transpose_kernel<<<dim3(P / 32, H / 32, 1), 256, 0, stream>>>(wt, wt, Wb, Wb, H, P);
        gemm_bf16_kernel<<<dim3(512), 256, 0, stream>>>(
            X, X, Wb, Wb, biast, biast, outt, outt, M, P, H);
    }
}

// Round 3
// 536.138 us; speedup vs baseline: 1.0891x; 1.0356x over previous
//
#include <hip/hip_runtime.h>
#include <hip/hip_bf16.h>
#include <stdint.h>

#define LN_EPS 1e-6f

typedef __bf16 bf16x8 __attribute__((ext_vector_type(8)));
typedef float f32x4 __attribute__((ext_vector_type(4)));

// float -> bf16 (RNE)
__device__ __forceinline__ unsigned short f2bf(float f) {
    uint32_t u = __float_as_uint(f);
    uint32_t r = (u + 0x7fffu + ((u >> 16) & 1u)) >> 16;
    return (unsigned short)r;
}

// async 16B global -> LDS (wave-uniform LDS base + lane*16 semantics)
__device__ __forceinline__ void async_copy16(const void* g, void* l) {
    const __attribute__((address_space(1))) uint32_t* gp =
        (const __attribute__((address_space(1))) uint32_t*)(uintptr_t)g;
    __attribute__((address_space(3))) uint32_t* lp =
        (__attribute__((address_space(3))) uint32_t*)(uint32_t)(uintptr_t)l;
    __builtin_amdgcn_global_load_lds(gp, lp, 16, 0, 0);
}

// ---------------- LayerNorm + cast to bf16: one WAVE per row ----------------
// No __syncthreads; 16 float4 in flight per lane; pure shfl reduction.
__global__ __launch_bounds__(256) void ln_bf16_kernel(
    const float* __restrict__ x0, const float* __restrict__ x1,
    const float* __restrict__ s0, const float* __restrict__ b0,
    const float* __restrict__ s1, const float* __restrict__ b1,
    unsigned short* __restrict__ y0, unsigned short* __restrict__ y1, int H)
{
    int wave = threadIdx.x >> 6, lane = threadIdx.x & 63;
    int row = blockIdx.x * 4 + wave;
    int prob = blockIdx.y;
    const float* x = (prob ? x1 : x0) + (size_t)row * H;
    const float* s = prob ? s1 : s0;
    const float* b = prob ? b1 : b0;
    unsigned short* y = (prob ? y1 : y0) + (size_t)row * H;

    float4 v[16];
    float sum = 0.f, sq = 0.f;
#pragma unroll
    for (int g = 0; g < 16; ++g) {
        v[g] = ((const float4*)x)[lane + 64 * g];
        sum += v[g].x + v[g].y + v[g].z + v[g].w;
        sq  += v[g].x * v[g].x + v[g].y * v[g].y + v[g].z * v[g].z + v[g].w * v[g].w;
    }
#pragma unroll
    for (int off = 32; off > 0; off >>= 1) {
        sum += __shfl_xor(sum, off, 64);
        sq  += __shfl_xor(sq, off, 64);
    }
    float mu = sum * (1.0f / 4096.0f);
    float var = sq * (1.0f / 4096.0f) - mu * mu;
    float rstd = rsqrtf(var + LN_EPS);

#pragma unroll
    for (int g = 0; g < 16; ++g) {
        int i4 = lane + 64 * g;
        float4 sc = ((const float4*)s)[i4];
        float4 bi = ((const float4*)b)[i4];
        ushort4 o;
        o.x = f2bf((v[g].x - mu) * rstd * sc.x + bi.x);
        o.y = f2bf((v[g].y - mu) * rstd * sc.y + bi.y);
        o.z = f2bf((v[g].z - mu) * rstd * sc.z + bi.z);
        o.w = f2bf((v[g].w - mu) * rstd * sc.w + bi.w);
        ((ushort4*)y)[i4] = o;
    }
}

// ---------------- cast + transpose W (K x N fp32) -> Wt (N x K bf16) ----------------
__global__ __launch_bounds__(256) void cast_transpose_kernel(
    const float* __restrict__ w0, const float* __restrict__ w1,
    unsigned short* __restrict__ o0, unsigned short* __restrict__ o1,
    int K, int N)
{
    int prob = blockIdx.z;
    const float* w = prob ? w1 : w0;
    unsigned short* o = prob ? o1 : o0;
    __shared__ unsigned short tile[32][33];
    int tx = threadIdx.x & 31;
    int ty = threadIdx.x >> 5;
    int n0 = blockIdx.x * 32;
    int k0 = blockIdx.y * 32;
#pragma unroll
    for (int i = 0; i < 4; ++i) {
        int k = ty + 8 * i;
        tile[k][tx] = f2bf(w[(size_t)(k0 + k) * N + n0 + tx]);
    }
    __syncthreads();
#pragma unroll
    for (int i = 0; i < 4; ++i) {
        int n = ty + 8 * i;
        o[(size_t)(n0 + n) * K + k0 + tx] = tile[tx][n];
    }
}

// ---------------- bf16 GEMM: out[M,N] = A[M,K] * Wt[N,K]^T + bias ----------------
// 1-D grid, XCD-aware swizzle, 128x128x64 tiles, XOR-swizzled LDS K-chunks.
#define BM 128
#define BN 128
#define BK 64

__global__ __launch_bounds__(256) void gemm_bf16_kernel(
    const unsigned short* __restrict__ A0, const unsigned short* __restrict__ A1,
    const unsigned short* __restrict__ W0, const unsigned short* __restrict__ W1,
    const float* __restrict__ bias0, const float* __restrict__ bias1,
    float* __restrict__ out0, float* __restrict__ out1,
    int M, int N, int K)
{
    // XCD-aware decode: xcd = id&7 owns m-tiles [xcd*8, xcd*8+8); n varies fastest.
    int id = blockIdx.x;
    int xcd = id & 7;
    int l = id >> 3;
    int prob = l >> 6;
    int rem = l & 63;
    int mt = xcd * 8 + (rem >> 3);
    int nt = rem & 7;

    const unsigned short* A = prob ? A1 : A0;
    const unsigned short* W = prob ? W1 : W0;
    const float* bias = prob ? bias1 : bias0;
    float* out = prob ? out1 : out0;

    __shared__ unsigned short As[BM * BK];  // [row][k-slot], 128B/row, XOR-swizzled slots
    __shared__ unsigned short Bs[BN * BK];

    int t = threadIdx.x;
    int wave = t >> 6, lane = t & 63;
    int quad = lane >> 4, r16 = lane & 15;
    int wm = wave >> 1, wn = wave & 1;
    int kx = r16 & 7;  // row&7 for all fragment rows this lane touches

    int tile_m = mt * BM;
    int tile_n = nt * BN;

    // staging: LDS slot (row, kb) receives GLOBAL k-chunk kb ^ (row&7).
    // lanes still cover each 128B global row-segment fully (permuted) -> coalesced.
    const unsigned short* ga[4];
    const unsigned short* gb[4];
#pragma unroll
    for (int q = 0; q < 4; ++q) {
        int cc = q * 256 + t;
        int row = cc >> 3, kb = cc & 7;
        int kbg = kb ^ (row & 7);
        ga[q] = A + (size_t)(tile_m + row) * K + kbg * 8;
        gb[q] = W + (size_t)(tile_n + row) * K + kbg * 8;
    }

    f32x4 acc[4][4] = {};

    for (int k0 = 0; k0 < K; k0 += BK) {
#pragma unroll
        for (int q = 0; q < 4; ++q) {
            uint32_t lbase = (uint32_t)(q * 256 + wave * 64) * 16;  // wave-uniform
            async_copy16(ga[q] + k0, (char*)As + lbase);
            async_copy16(gb[q] + k0, (char*)Bs + lbase);
        }
        __syncthreads();

#pragma unroll
        for (int s = 0; s < 2; ++s) {
            bf16x8 af[4], bfr[4];
#pragma unroll
            for (int i = 0; i < 4; ++i) {
                int ka = (s * 4 + quad) ^ kx;  // slot holding global chunk s*4+quad
                af[i]  = *(const bf16x8*)(As + (wm * 64 + i * 16 + r16) * 64 + ka * 8);
                bfr[i] = *(const bf16x8*)(Bs + (wn * 64 + i * 16 + r16) * 64 + ka * 8);
            }
#pragma unroll
            for (int i = 0; i < 4; ++i)
#pragma unroll
                for (int j = 0; j < 4; ++j)
                    acc[i][j] = __builtin_amdgcn_mfma_f32_16x16x32_bf16(af[i], bfr[j], acc[i][j], 0, 0, 0);
        }
        __syncthreads();
    }

    // epilogue: C mapping col=lane&15, row=quad*4+reg
#pragma unroll
    for (int j = 0; j < 4; ++j) {
        int col = tile_n + wn * 64 + j * 16 + r16;
        float bj = bias[col];
#pragma unroll
        for (int i = 0; i < 4; ++i) {
            int row = tile_m + wm * 64 + i * 16 + quad * 4;
#pragma unroll
            for (int r = 0; r < 4; ++r)
                out[(size_t)(row + r) * N + col] = acc[i][j][r] + bj;
        }
    }
}

extern "C" void kernel_launch(void* const* d_in, const int* in_sizes, int n_in,
                              void* d_out, int out_size, void* d_ws, size_t ws_size,
                              hipStream_t stream) {
    const float* xv = (const float*)d_in[0];
    const float* xt = (const float*)d_in[1];
    const float* sv = (const float*)d_in[2];
    const float* bv = (const float*)d_in[3];
    const float* wv = (const float*)d_in[4];
    const float* biasv = (const float*)d_in[5];
    const float* st = (const float*)d_in[6];
    const float* bt = (const float*)d_in[7];
    const float* wt = (const float*)d_in[8];
    const float* biast = (const float*)d_in[9];
    float* out = (float*)d_out;

    const int B = 2, S = 4096, H = 4096, P = 1024;
    const int M = B * S;  // 8192
    float* outv = out;
    float* outt = out + (size_t)M * P;

    size_t xnBytes = (size_t)M * H * 2;  // 64 MiB per problem
    size_t wtBytes = (size_t)P * H * 2;  // 8 MiB per problem
    char* ws = (char*)d_ws;

    if (ws_size >= 2 * xnBytes + 2 * wtBytes) {
        unsigned short* Xv = (unsigned short*)(ws);
        unsigned short* Xt = (unsigned short*)(ws + xnBytes);
        unsigned short* Wv = (unsigned short*)(ws + 2 * xnBytes);
        unsigned short* Wt = (unsigned short*)(ws + 2 * xnBytes + wtBytes);
        ln_bf16_kernel<<<dim3(M / 4, 2), 256, 0, stream>>>(xv, xt, sv, bv, st, bt, Xv, Xt, H);
        cast_transpose_kernel<<<dim3(P / 32, H / 32, 2), 256, 0, stream>>>(wv, wt, Wv, Wt, H, P);
        gemm_bf16_kernel<<<dim3(1024), 256, 0, stream>>>(
            Xv, Xt, Wv, Wt, biasv, biast, outv, outt, M, P, H);
    } else {
        unsigned short* X  = (unsigned short*)(ws);
        unsigned short* Wb = (unsigned short*)(ws + xnBytes);
        ln_bf16_kernel<<<dim3(M / 4, 1), 256, 0, stream>>>(xv, xv, sv, bv, sv, bv, X, X, H);
        cast_transpose_kernel<<<dim3(P / 32, H / 32, 1), 256, 0, stream>>>(wv, wv, Wb, Wb, H, P);
        gemm_bf16_kernel<<<dim3(512), 256, 0, stream>>>(
            X, X, Wb, Wb, biasv, biasv, outv, outv, M, P, H);
        ln_bf16_kernel<<<dim3(M / 4, 1), 256, 0, stream>>>(xt, xt, st, bt, st, bt, X, X, H);
        cast_transpose_kernel<<<dim3(P / 32, H / 32, 1), 256, 0, stream>>>(wt, wt, Wb, Wb, H, P);
        gemm_bf16_kernel<<<dim3(512), 256, 0, stream>>>(
            X, X, Wb, Wb, biast, biast, outt, outt, M, P, H);
    }
}